// Round 3
// baseline (689.869 us; speedup 1.0000x reference)
//
#include <hip/hip_runtime.h>

#define N_NODES 100000
#define N_EDGES 1200000
#define LAYERS 4
#define SLOPE 0.01f

#define SCAN_ELEMS 1024                      // elems per scan1 block (256 thr x 4)
#define NB1 ((N_NODES + SCAN_ELEMS - 1) / SCAN_ELEMS)   // 98

__device__ __forceinline__ float leaky(float v) { return v >= 0.f ? v : SLOPE * v; }

// ---------------------------------------------------------------------------
// CSR build (counting sort by edge_dst) — runs once per launch
// ---------------------------------------------------------------------------
__global__ __launch_bounds__(256) void zero_counts(int* __restrict__ counts)
{
    int i = blockIdx.x * 256 + threadIdx.x;
    if (i < N_NODES) counts[i] = 0;
}

__global__ __launch_bounds__(256) void count_kernel(
    const int* __restrict__ dst, int* __restrict__ counts)
{
    int e = blockIdx.x * 256 + threadIdx.x;
    if (e < N_EDGES) atomicAdd(&counts[dst[e]], 1);
}

__global__ __launch_bounds__(256) void scan1_kernel(
    const int* __restrict__ counts, int* __restrict__ offs, int* __restrict__ bsum)
{
    __shared__ int s[256];
    int b = blockIdx.x, t = threadIdx.x;
    int base = b * SCAN_ELEMS;
    int v[4]; int sum = 0;
    #pragma unroll
    for (int u = 0; u < 4; u++) {
        int idx = base + t * 4 + u;
        int c = (idx < N_NODES) ? counts[idx] : 0;
        v[u] = sum; sum += c;
    }
    s[t] = sum; __syncthreads();
    for (int off = 1; off < 256; off <<= 1) {
        int y = (t >= off) ? s[t - off] : 0;
        __syncthreads();
        s[t] += y;
        __syncthreads();
    }
    int excl = s[t] - sum;
    #pragma unroll
    for (int u = 0; u < 4; u++) {
        int idx = base + t * 4 + u;
        if (idx < N_NODES) offs[idx] = excl + v[u];
    }
    if (t == 255) bsum[b] = s[255];
}

__global__ __launch_bounds__(128) void scan2_kernel(
    const int* __restrict__ bsum, int* __restrict__ bscan)
{
    __shared__ int s[128];
    int t = threadIdx.x;
    int c = (t < NB1) ? bsum[t] : 0;
    s[t] = c; __syncthreads();
    for (int off = 1; off < 128; off <<= 1) {
        int y = (t >= off) ? s[t - off] : 0;
        __syncthreads();
        s[t] += y;
        __syncthreads();
    }
    if (t < NB1) bscan[t] = s[t] - c;
}

__global__ __launch_bounds__(256) void scan3_kernel(
    int* __restrict__ offs, int* __restrict__ cursor, const int* __restrict__ bscan)
{
    int b = blockIdx.x, t = threadIdx.x;
    int base = b * SCAN_ELEMS;
    int add = bscan[b];
    #pragma unroll
    for (int u = 0; u < 4; u++) {
        int idx = base + t * 4 + u;
        if (idx < N_NODES) {
            int v = offs[idx] + add;
            offs[idx] = v;
            cursor[idx] = v;
        }
    }
    if (b == 0 && t == 0) offs[N_NODES] = N_EDGES;
}

// fill: one packed 8B (src, w) store per edge — halves random dirty lines
__global__ __launch_bounds__(256) void fill_kernel(
    const int* __restrict__ src, const int* __restrict__ dst,
    const float* __restrict__ w, int* __restrict__ cursor,
    int2* __restrict__ ep)
{
    int e = blockIdx.x * 256 + threadIdx.x;
    if (e >= N_EDGES) return;
    int d = dst[e];
    int p = atomicAdd(&cursor[d], 1);
    ep[p] = make_int2(src[e], __float_as_int(w[e]));
}

// ---------------------------------------------------------------------------
// Kernel A: encoder + LN(layer0) + dual GEMM(layer0)
//   h = leaky(x@W1+b1)@W2+b2 ; hn = LN(h)*g+b -> H
//   Y = hn@nodeW + node_b + edge_b ; Z = hn@edgeW
// ---------------------------------------------------------------------------
__global__ __launch_bounds__(256) void enc_ln_gemm(
    const float* __restrict__ x,
    const float* __restrict__ W1, const float* __restrict__ b1,
    const float* __restrict__ W2, const float* __restrict__ b2,
    const float* __restrict__ ln_g, const float* __restrict__ ln_b,
    const float* __restrict__ nodeW, const float* __restrict__ node_b,
    const float* __restrict__ edgeW, const float* __restrict__ edge_b,
    float* __restrict__ H, float* __restrict__ Y, float* __restrict__ Z)
{
    __shared__ float sW1[128 * 16];   // [k][i] = W1[i][k]
    __shared__ float sW2[128 * 64];
    __shared__ float sNW[64 * 32];
    __shared__ float sEW[64 * 32];
    __shared__ float sb1[128];
    __shared__ float sb2[64];
    __shared__ float sg[64], sb[64], sby[32];
    for (int idx = threadIdx.x; idx < 16 * 128; idx += 256) {
        int i = idx / 128, k = idx % 128;
        sW1[k * 16 + i] = W1[idx];
    }
    for (int idx = threadIdx.x; idx < 128 * 64; idx += 256) sW2[idx] = W2[idx];
    for (int idx = threadIdx.x; idx < 64 * 32; idx += 256) {
        sNW[idx] = nodeW[idx];
        sEW[idx] = edgeW[idx];
    }
    if (threadIdx.x < 128) sb1[threadIdx.x] = b1[threadIdx.x];
    if (threadIdx.x < 64) {
        sb2[threadIdx.x] = b2[threadIdx.x];
        sg[threadIdx.x] = ln_g[threadIdx.x];
        sb[threadIdx.x] = ln_b[threadIdx.x];
    }
    if (threadIdx.x < 32) sby[threadIdx.x] = node_b[threadIdx.x] + edge_b[threadIdx.x];
    __syncthreads();

    int n = blockIdx.x * 256 + threadIdx.x;
    if (n >= N_NODES) return;

    float xi[16];
    const float4* xv = (const float4*)(x + (size_t)n * 16);
    #pragma unroll
    for (int i = 0; i < 4; i++) {
        float4 t = xv[i];
        xi[4 * i] = t.x; xi[4 * i + 1] = t.y; xi[4 * i + 2] = t.z; xi[4 * i + 3] = t.w;
    }
    float h[64];
    #pragma unroll
    for (int j = 0; j < 64; j++) h[j] = sb2[j];

    for (int k = 0; k < 128; k++) {
        float t = sb1[k];
        const float4* w1r = (const float4*)(sW1 + k * 16);
        #pragma unroll
        for (int i = 0; i < 4; i++) {
            float4 w = w1r[i];
            t += xi[4 * i] * w.x + xi[4 * i + 1] * w.y + xi[4 * i + 2] * w.z + xi[4 * i + 3] * w.w;
        }
        t = leaky(t);
        const float4* w2r = (const float4*)(sW2 + k * 64);
        #pragma unroll
        for (int j = 0; j < 16; j++) {
            float4 w = w2r[j];
            h[4 * j] += t * w.x; h[4 * j + 1] += t * w.y;
            h[4 * j + 2] += t * w.z; h[4 * j + 3] += t * w.w;
        }
    }

    // LN + dual GEMM
    float s = 0.f, s2 = 0.f;
    #pragma unroll
    for (int j = 0; j < 64; j++) { s += h[j]; s2 += h[j] * h[j]; }
    float mu  = s * (1.f / 64.f);
    float var = s2 * (1.f / 64.f) - mu * mu;
    float rs  = rsqrtf(var + 1e-5f);

    float accY[32], accZ[32];
    #pragma unroll
    for (int j = 0; j < 32; j++) { accY[j] = sby[j]; accZ[j] = 0.f; }

    float4* hnv = (float4*)(H + (size_t)n * 64);
    #pragma unroll
    for (int k = 0; k < 64; k++) {
        float hnk = (h[k] - mu) * rs * sg[k] + sb[k];
        h[k] = hnk;
        const float4* nwr = (const float4*)(sNW + k * 32);
        const float4* ewr = (const float4*)(sEW + k * 32);
        #pragma unroll
        for (int j = 0; j < 8; j++) {
            float4 wn = nwr[j];
            float4 we = ewr[j];
            accY[4 * j]     += hnk * wn.x; accY[4 * j + 1] += hnk * wn.y;
            accY[4 * j + 2] += hnk * wn.z; accY[4 * j + 3] += hnk * wn.w;
            accZ[4 * j]     += hnk * we.x; accZ[4 * j + 1] += hnk * we.y;
            accZ[4 * j + 2] += hnk * we.z; accZ[4 * j + 3] += hnk * we.w;
        }
    }
    #pragma unroll
    for (int j = 0; j < 16; j++)
        hnv[j] = make_float4(h[4 * j], h[4 * j + 1], h[4 * j + 2], h[4 * j + 3]);
    float4* yv = (float4*)(Y + (size_t)n * 32);
    float4* zv = (float4*)(Z + (size_t)n * 32);
    #pragma unroll
    for (int j = 0; j < 8; j++) {
        yv[j] = make_float4(accY[4 * j], accY[4 * j + 1], accY[4 * j + 2], accY[4 * j + 3]);
        zv[j] = make_float4(accZ[4 * j], accZ[4 * j + 1], accZ[4 * j + 2], accZ[4 * j + 3]);
    }
}

// ---------------------------------------------------------------------------
// Gather: Y[n] += sum over incoming edges of w_e * Z[src_e]
// 8 lanes per node; lanes read consecutive float4s of a Z row (128B/edge).
// ---------------------------------------------------------------------------
__global__ __launch_bounds__(256) void gather_kernel(
    const int* __restrict__ offs, const int2* __restrict__ ep,
    const float* __restrict__ Z, float* __restrict__ Y)
{
    int gid = blockIdx.x * 256 + threadIdx.x;
    int node = gid >> 3;
    int lane = gid & 7;
    if (node >= N_NODES) return;
    int p0 = offs[node], p1 = offs[node + 1];
    float4 acc = make_float4(0.f, 0.f, 0.f, 0.f);
    for (int p = p0; p < p1; p++) {
        int2 pr = ep[p];
        float we = __int_as_float(pr.y);
        float4 zv = ((const float4*)Z)[(size_t)pr.x * 8 + lane];
        acc.x += we * zv.x; acc.y += we * zv.y;
        acc.z += we * zv.z; acc.w += we * zv.w;
    }
    float4* yp = (float4*)(Y + (size_t)node * 32) + lane;
    float4 y = *yp;
    y.x += acc.x; y.y += acc.y; y.z += acc.z; y.w += acc.w;
    *yp = y;
}

// ---------------------------------------------------------------------------
// Kernel B: mlp+residual of layer l, then LN + dual GEMM of layer l+1.
//   h = leaky(Y)@mlpW + mlp_b + hn(H) ; hn' = LN(h) -> H (in-place)
//   Y = hn'@nodeW + node_b + edge_b (in-place) ; Z = hn'@edgeW
// ---------------------------------------------------------------------------
__global__ __launch_bounds__(256) void mlp_ln_gemm(
    float* __restrict__ Yio, float* __restrict__ H, float* __restrict__ Z,
    const float* __restrict__ mlpW, const float* __restrict__ mlp_b,
    const float* __restrict__ ln_g, const float* __restrict__ ln_b,
    const float* __restrict__ nodeW, const float* __restrict__ node_b,
    const float* __restrict__ edgeW, const float* __restrict__ edge_b)
{
    __shared__ float sMW[32 * 64];
    __shared__ float sNW[64 * 32];
    __shared__ float sEW[64 * 32];
    __shared__ float smb[64], sg[64], sb[64], sby[32];
    for (int idx = threadIdx.x; idx < 32 * 64; idx += 256) sMW[idx] = mlpW[idx];
    for (int idx = threadIdx.x; idx < 64 * 32; idx += 256) {
        sNW[idx] = nodeW[idx];
        sEW[idx] = edgeW[idx];
    }
    if (threadIdx.x < 64) {
        smb[threadIdx.x] = mlp_b[threadIdx.x];
        sg[threadIdx.x] = ln_g[threadIdx.x];
        sb[threadIdx.x] = ln_b[threadIdx.x];
    }
    if (threadIdx.x < 32) sby[threadIdx.x] = node_b[threadIdx.x] + edge_b[threadIdx.x];
    __syncthreads();

    int n = blockIdx.x * 256 + threadIdx.x;
    if (n >= N_NODES) return;

    float ly[32];
    const float4* yv = (const float4*)(Yio + (size_t)n * 32);
    #pragma unroll
    for (int i = 0; i < 8; i++) {
        float4 t = yv[i];
        ly[4 * i] = leaky(t.x); ly[4 * i + 1] = leaky(t.y);
        ly[4 * i + 2] = leaky(t.z); ly[4 * i + 3] = leaky(t.w);
    }
    float h[64];
    #pragma unroll
    for (int j = 0; j < 64; j++) h[j] = smb[j];
    for (int k = 0; k < 32; k++) {
        float t = ly[k];
        const float4* wr = (const float4*)(sMW + k * 64);
        #pragma unroll
        for (int j = 0; j < 16; j++) {
            float4 wv = wr[j];
            h[4 * j] += t * wv.x; h[4 * j + 1] += t * wv.y;
            h[4 * j + 2] += t * wv.z; h[4 * j + 3] += t * wv.w;
        }
    }
    // residual
    float4* hp = (float4*)(H + (size_t)n * 64);
    #pragma unroll
    for (int j = 0; j < 16; j++) {
        float4 hn = hp[j];
        h[4 * j] += hn.x; h[4 * j + 1] += hn.y; h[4 * j + 2] += hn.z; h[4 * j + 3] += hn.w;
    }
    // LN
    float s = 0.f, s2 = 0.f;
    #pragma unroll
    for (int j = 0; j < 64; j++) { s += h[j]; s2 += h[j] * h[j]; }
    float mu  = s * (1.f / 64.f);
    float var = s2 * (1.f / 64.f) - mu * mu;
    float rs  = rsqrtf(var + 1e-5f);

    float accY[32], accZ[32];
    #pragma unroll
    for (int j = 0; j < 32; j++) { accY[j] = sby[j]; accZ[j] = 0.f; }

    #pragma unroll
    for (int k = 0; k < 64; k++) {
        float hnk = (h[k] - mu) * rs * sg[k] + sb[k];
        h[k] = hnk;
        const float4* nwr = (const float4*)(sNW + k * 32);
        const float4* ewr = (const float4*)(sEW + k * 32);
        #pragma unroll
        for (int j = 0; j < 8; j++) {
            float4 wn = nwr[j];
            float4 we = ewr[j];
            accY[4 * j]     += hnk * wn.x; accY[4 * j + 1] += hnk * wn.y;
            accY[4 * j + 2] += hnk * wn.z; accY[4 * j + 3] += hnk * wn.w;
            accZ[4 * j]     += hnk * we.x; accZ[4 * j + 1] += hnk * we.y;
            accZ[4 * j + 2] += hnk * we.z; accZ[4 * j + 3] += hnk * we.w;
        }
    }
    #pragma unroll
    for (int j = 0; j < 16; j++)
        hp[j] = make_float4(h[4 * j], h[4 * j + 1], h[4 * j + 2], h[4 * j + 3]);
    float4* yo = (float4*)(Yio + (size_t)n * 32);
    float4* zv = (float4*)(Z + (size_t)n * 32);
    #pragma unroll
    for (int j = 0; j < 8; j++) {
        yo[j] = make_float4(accY[4 * j], accY[4 * j + 1], accY[4 * j + 2], accY[4 * j + 3]);
        zv[j] = make_float4(accZ[4 * j], accZ[4 * j + 1], accZ[4 * j + 2], accZ[4 * j + 3]);
    }
}

// ---------------------------------------------------------------------------
// Kernel C: mlp+residual of layer 3, then decoder.
//   h = leaky(Y)@mlpW + mlp_b + hn(H) ; out = leaky(h@dW1+db1)@dW2+db2
// ---------------------------------------------------------------------------
__global__ __launch_bounds__(256) void mlp_dec(
    const float* __restrict__ Y, const float* __restrict__ H,
    const float* __restrict__ mlpW, const float* __restrict__ mlp_b,
    const float* __restrict__ dW1, const float* __restrict__ db1,
    const float* __restrict__ dW2, const float* __restrict__ db2,
    float* __restrict__ out)
{
    __shared__ float sMW[32 * 64];
    __shared__ float smb[64];
    __shared__ float sW1t[24 * 64];   // [t][k] = dW1[k][t]
    __shared__ float sb1[24];
    __shared__ float sW2[24 * 3];
    __shared__ float sb2v[3];
    for (int idx = threadIdx.x; idx < 32 * 64; idx += 256) sMW[idx] = mlpW[idx];
    for (int idx = threadIdx.x; idx < 64 * 24; idx += 256) {
        int k = idx / 24, t = idx % 24;
        sW1t[t * 64 + k] = dW1[idx];
    }
    if (threadIdx.x < 64) smb[threadIdx.x] = mlp_b[threadIdx.x];
    if (threadIdx.x < 24) sb1[threadIdx.x] = db1[threadIdx.x];
    if (threadIdx.x < 72) sW2[threadIdx.x] = dW2[threadIdx.x];
    if (threadIdx.x < 3)  sb2v[threadIdx.x] = db2[threadIdx.x];
    __syncthreads();

    int n = blockIdx.x * 256 + threadIdx.x;
    if (n >= N_NODES) return;

    float ly[32];
    const float4* yv = (const float4*)(Y + (size_t)n * 32);
    #pragma unroll
    for (int i = 0; i < 8; i++) {
        float4 t = yv[i];
        ly[4 * i] = leaky(t.x); ly[4 * i + 1] = leaky(t.y);
        ly[4 * i + 2] = leaky(t.z); ly[4 * i + 3] = leaky(t.w);
    }
    float h[64];
    #pragma unroll
    for (int j = 0; j < 64; j++) h[j] = smb[j];
    for (int k = 0; k < 32; k++) {
        float t = ly[k];
        const float4* wr = (const float4*)(sMW + k * 64);
        #pragma unroll
        for (int j = 0; j < 16; j++) {
            float4 wv = wr[j];
            h[4 * j] += t * wv.x; h[4 * j + 1] += t * wv.y;
            h[4 * j + 2] += t * wv.z; h[4 * j + 3] += t * wv.w;
        }
    }
    const float4* hp = (const float4*)(H + (size_t)n * 64);
    #pragma unroll
    for (int j = 0; j < 16; j++) {
        float4 hn = hp[j];
        h[4 * j] += hn.x; h[4 * j + 1] += hn.y; h[4 * j + 2] += hn.z; h[4 * j + 3] += hn.w;
    }
    // decoder
    float hid[24];
    #pragma unroll
    for (int t = 0; t < 24; t++) hid[t] = sb1[t];
    #pragma unroll
    for (int i = 0; i < 16; i++) {
        #pragma unroll
        for (int t = 0; t < 24; t++) {
            float4 wv = *(const float4*)(sW1t + t * 64 + 4 * i);
            hid[t] += h[4 * i] * wv.x + h[4 * i + 1] * wv.y + h[4 * i + 2] * wv.z + h[4 * i + 3] * wv.w;
        }
    }
    float o0 = sb2v[0], o1 = sb2v[1], o2 = sb2v[2];
    #pragma unroll
    for (int t = 0; t < 24; t++) {
        float lt = leaky(hid[t]);
        o0 += lt * sW2[t * 3 + 0];
        o1 += lt * sW2[t * 3 + 1];
        o2 += lt * sW2[t * 3 + 2];
    }
    float* op = out + (size_t)n * 3;
    op[0] = o0; op[1] = o1; op[2] = o2;
}

// ---------------------------------------------------------------------------
extern "C" void kernel_launch(void* const* d_in, const int* in_sizes, int n_in,
                              void* d_out, int out_size, void* d_ws, size_t ws_size,
                              hipStream_t stream)
{
    const float* x      = (const float*)d_in[0];
    const int*   esrc   = (const int*)d_in[2];
    const int*   edst   = (const int*)d_in[3];
    const float* ew     = (const float*)d_in[4];
    const float* enc_W1 = (const float*)d_in[5];
    const float* enc_b1 = (const float*)d_in[6];
    const float* enc_W2 = (const float*)d_in[7];
    const float* enc_b2 = (const float*)d_in[8];
    const float* dec_W1 = (const float*)d_in[9];
    const float* dec_b1 = (const float*)d_in[10];
    const float* dec_W2 = (const float*)d_in[11];
    const float* dec_b2 = (const float*)d_in[12];
    const float* ln_g   = (const float*)d_in[13];
    const float* ln_b   = (const float*)d_in[14];
    const float* node_W = (const float*)d_in[15];
    const float* node_b = (const float*)d_in[16];
    const float* edge_W = (const float*)d_in[17];
    const float* edge_b = (const float*)d_in[18];
    const float* mlp_W  = (const float*)d_in[19];
    const float* mlp_b  = (const float*)d_in[20];

    // Workspace: floats H[N*64] | Y[N*32] | Z[N*32] | ep[E int2]
    //            ints counts[N] | offs[N+1] | cursor[N] | bsum | bscan
    float* H  = (float*)d_ws;
    float* Y  = H + (size_t)N_NODES * 64;
    float* Z  = Y + (size_t)N_NODES * 32;
    int2*  ep = (int2*)(Z + (size_t)N_NODES * 32);
    int* counts = (int*)(ep + N_EDGES);
    int* offs   = counts + N_NODES;          // N_NODES+1 entries
    int* cursor = offs + N_NODES + 1;
    int* bsum   = cursor + N_NODES;
    int* bscan  = bsum + NB1;

    const int nodeBlocks   = (N_NODES + 255) / 256;
    const int edgeBlocks   = (N_EDGES + 255) / 256;
    const int gatherBlocks = (N_NODES * 8 + 255) / 256;

    // --- CSR build (counting sort by dst) ---
    zero_counts<<<nodeBlocks, 256, 0, stream>>>(counts);
    count_kernel<<<edgeBlocks, 256, 0, stream>>>(edst, counts);
    scan1_kernel<<<NB1, 256, 0, stream>>>(counts, offs, bsum);
    scan2_kernel<<<1, 128, 0, stream>>>(bsum, bscan);
    scan3_kernel<<<NB1, 256, 0, stream>>>(offs, cursor, bscan);
    fill_kernel<<<edgeBlocks, 256, 0, stream>>>(esrc, edst, ew, cursor, ep);

    // --- network ---
    enc_ln_gemm<<<nodeBlocks, 256, 0, stream>>>(
        x, enc_W1, enc_b1, enc_W2, enc_b2,
        ln_g, ln_b, node_W, node_b, edge_W, edge_b, H, Y, Z);

    for (int l = 0; l < LAYERS - 1; l++) {
        gather_kernel<<<gatherBlocks, 256, 0, stream>>>(offs, ep, Z, Y);
        mlp_ln_gemm<<<nodeBlocks, 256, 0, stream>>>(
            Y, H, Z,
            mlp_W + l * 32 * 64, mlp_b + l * 64,
            ln_g + (l + 1) * 64, ln_b + (l + 1) * 64,
            node_W + (l + 1) * 64 * 32, node_b + (l + 1) * 32,
            edge_W + (l + 1) * 64 * 32, edge_b + (l + 1) * 32);
    }
    gather_kernel<<<gatherBlocks, 256, 0, stream>>>(offs, ep, Z, Y);
    mlp_dec<<<nodeBlocks, 256, 0, stream>>>(
        Y, H, mlp_W + 3 * 32 * 64, mlp_b + 3 * 64,
        dec_W1, dec_b1, dec_W2, dec_b2, (float*)d_out);
}

// Round 4
// 591.726 us; speedup vs baseline: 1.1659x; 1.1659x over previous
//
#include <hip/hip_runtime.h>

#define N_NODES 100000
#define N_EDGES 1200000
#define LAYERS 4
#define SLOPE 0.01f

#define SCAN_ELEMS 1024                      // elems per scan1 block (256 thr x 4)
#define NB1 ((N_NODES + SCAN_ELEMS - 1) / SCAN_ELEMS)   // 98

__device__ __forceinline__ float leaky(float v) { return v >= 0.f ? v : SLOPE * v; }

// ---------------------------------------------------------------------------
// CSR build (counting sort by edge_dst) — runs once per launch
// ---------------------------------------------------------------------------
__global__ __launch_bounds__(256) void zero_counts(int* __restrict__ counts)
{
    int i = blockIdx.x * 256 + threadIdx.x;
    if (i < N_NODES) counts[i] = 0;
}

__global__ __launch_bounds__(256) void count_kernel(
    const int* __restrict__ dst, int* __restrict__ counts)
{
    int e = blockIdx.x * 256 + threadIdx.x;
    if (e < N_EDGES) atomicAdd(&counts[dst[e]], 1);
}

__global__ __launch_bounds__(256) void scan1_kernel(
    const int* __restrict__ counts, int* __restrict__ offs, int* __restrict__ bsum)
{
    __shared__ int s[256];
    int b = blockIdx.x, t = threadIdx.x;
    int base = b * SCAN_ELEMS;
    int v[4]; int sum = 0;
    #pragma unroll
    for (int u = 0; u < 4; u++) {
        int idx = base + t * 4 + u;
        int c = (idx < N_NODES) ? counts[idx] : 0;
        v[u] = sum; sum += c;
    }
    s[t] = sum; __syncthreads();
    for (int off = 1; off < 256; off <<= 1) {
        int y = (t >= off) ? s[t - off] : 0;
        __syncthreads();
        s[t] += y;
        __syncthreads();
    }
    int excl = s[t] - sum;
    #pragma unroll
    for (int u = 0; u < 4; u++) {
        int idx = base + t * 4 + u;
        if (idx < N_NODES) offs[idx] = excl + v[u];
    }
    if (t == 255) bsum[b] = s[255];
}

__global__ __launch_bounds__(128) void scan2_kernel(
    const int* __restrict__ bsum, int* __restrict__ bscan)
{
    __shared__ int s[128];
    int t = threadIdx.x;
    int c = (t < NB1) ? bsum[t] : 0;
    s[t] = c; __syncthreads();
    for (int off = 1; off < 128; off <<= 1) {
        int y = (t >= off) ? s[t - off] : 0;
        __syncthreads();
        s[t] += y;
        __syncthreads();
    }
    if (t < NB1) bscan[t] = s[t] - c;
}

__global__ __launch_bounds__(256) void scan3_kernel(
    int* __restrict__ offs, int* __restrict__ cursor, const int* __restrict__ bscan)
{
    int b = blockIdx.x, t = threadIdx.x;
    int base = b * SCAN_ELEMS;
    int add = bscan[b];
    #pragma unroll
    for (int u = 0; u < 4; u++) {
        int idx = base + t * 4 + u;
        if (idx < N_NODES) {
            int v = offs[idx] + add;
            offs[idx] = v;
            cursor[idx] = v;
        }
    }
    if (b == 0 && t == 0) offs[N_NODES] = N_EDGES;
}

// fill: one packed 8B (src, w) store per edge
__global__ __launch_bounds__(256) void fill_kernel(
    const int* __restrict__ src, const int* __restrict__ dst,
    const float* __restrict__ w, int* __restrict__ cursor,
    int2* __restrict__ ep)
{
    int e = blockIdx.x * 256 + threadIdx.x;
    if (e >= N_EDGES) return;
    int d = dst[e];
    int p = atomicAdd(&cursor[d], 1);
    ep[p] = make_int2(src[e], __float_as_int(w[e]));
}

// ---------------------------------------------------------------------------
// Kernel A: encoder + LN(layer0) + dual GEMM(layer0).  4 lanes per node.
// Lane q owns features [q*16, q*16+16) of h/hn, Y/Z cols [q*8, q*8+8).
// ---------------------------------------------------------------------------
__global__ __launch_bounds__(256) void enc_ln_gemm(
    const float* __restrict__ x,
    const float* __restrict__ W1, const float* __restrict__ b1,
    const float* __restrict__ W2, const float* __restrict__ b2,
    const float* __restrict__ ln_g, const float* __restrict__ ln_b,
    const float* __restrict__ nodeW, const float* __restrict__ node_b,
    const float* __restrict__ edgeW, const float* __restrict__ edge_b,
    float* __restrict__ H, float* __restrict__ Y, float* __restrict__ Z)
{
    __shared__ float sW1t[128 * 16];   // [k][i] = W1[i][k]
    __shared__ float sW2[128 * 64];
    __shared__ float sNW[64 * 32];
    __shared__ float sEW[64 * 32];
    __shared__ float sb1[128];
    __shared__ float sb2[64];
    __shared__ float sg[64], sb[64], sby[32];
    for (int idx = threadIdx.x; idx < 16 * 128; idx += 256) {
        int i = idx / 128, k = idx % 128;
        sW1t[k * 16 + i] = W1[idx];
    }
    for (int idx = threadIdx.x; idx < 128 * 64; idx += 256) sW2[idx] = W2[idx];
    for (int idx = threadIdx.x; idx < 64 * 32; idx += 256) {
        sNW[idx] = nodeW[idx];
        sEW[idx] = edgeW[idx];
    }
    if (threadIdx.x < 128) sb1[threadIdx.x] = b1[threadIdx.x];
    if (threadIdx.x < 64) {
        sb2[threadIdx.x] = b2[threadIdx.x];
        sg[threadIdx.x] = ln_g[threadIdx.x];
        sb[threadIdx.x] = ln_b[threadIdx.x];
    }
    if (threadIdx.x < 32) sby[threadIdx.x] = node_b[threadIdx.x] + edge_b[threadIdx.x];
    __syncthreads();

    int gid = blockIdx.x * 256 + threadIdx.x;
    int node = gid >> 2;
    int q = gid & 3;
    if (node >= N_NODES) return;

    float xi[16];
    const float4* xv = (const float4*)(x + (size_t)node * 16);
    #pragma unroll
    for (int i = 0; i < 4; i++) {
        float4 t = xv[i];
        xi[4 * i] = t.x; xi[4 * i + 1] = t.y; xi[4 * i + 2] = t.z; xi[4 * i + 3] = t.w;
    }

    // hidden: lane q computes t = tt*4 + q (interleaved: quad reads hit
    // different banks); hid[tt] = leaky(x . W1[:,t] + b1[t])
    float hid[32];
    #pragma unroll
    for (int tt = 0; tt < 32; tt++) {
        int t = tt * 4 + q;
        const float4* w = (const float4*)(sW1t + t * 16);
        float a = sb1[t];
        float4 w0 = w[0], w1 = w[1], w2 = w[2], w3 = w[3];
        a += xi[0] * w0.x + xi[1] * w0.y + xi[2] * w0.z + xi[3] * w0.w;
        a += xi[4] * w1.x + xi[5] * w1.y + xi[6] * w1.z + xi[7] * w1.w;
        a += xi[8] * w2.x + xi[9] * w2.y + xi[10] * w2.z + xi[11] * w2.w;
        a += xi[12] * w3.x + xi[13] * w3.y + xi[14] * w3.z + xi[15] * w3.w;
        hid[tt] = leaky(a);
    }

    // h chunk: j in [q*16, q*16+16); t = kk*4 + ss broadcast via shfl
    float h[16];
    #pragma unroll
    for (int jj = 0; jj < 16; jj++) h[jj] = sb2[q * 16 + jj];
    #pragma unroll
    for (int kk = 0; kk < 32; kk++) {
        #pragma unroll
        for (int ss = 0; ss < 4; ss++) {
            float v = __shfl(hid[kk], ss, 4);
            const float4* w = (const float4*)(sW2 + (kk * 4 + ss) * 64 + q * 16);
            float4 a = w[0], b = w[1], c = w[2], d = w[3];
            h[0]  += v * a.x; h[1]  += v * a.y; h[2]  += v * a.z; h[3]  += v * a.w;
            h[4]  += v * b.x; h[5]  += v * b.y; h[6]  += v * b.z; h[7]  += v * b.w;
            h[8]  += v * c.x; h[9]  += v * c.y; h[10] += v * c.z; h[11] += v * c.w;
            h[12] += v * d.x; h[13] += v * d.y; h[14] += v * d.z; h[15] += v * d.w;
        }
    }

    // LN over quad
    float s = 0.f, s2 = 0.f;
    #pragma unroll
    for (int jj = 0; jj < 16; jj++) { s += h[jj]; s2 += h[jj] * h[jj]; }
    s  += __shfl_xor(s, 1, 4);  s  += __shfl_xor(s, 2, 4);
    s2 += __shfl_xor(s2, 1, 4); s2 += __shfl_xor(s2, 2, 4);
    float mu  = s * (1.f / 64.f);
    float var = s2 * (1.f / 64.f) - mu * mu;
    float rs  = rsqrtf(var + 1e-5f);

    float hn[16];
    #pragma unroll
    for (int jj = 0; jj < 16; jj++)
        hn[jj] = (h[jj] - mu) * rs * sg[q * 16 + jj] + sb[q * 16 + jj];

    float4* hs = (float4*)(H + (size_t)node * 64 + q * 16);
    #pragma unroll
    for (int c = 0; c < 4; c++)
        hs[c] = make_float4(hn[4 * c], hn[4 * c + 1], hn[4 * c + 2], hn[4 * c + 3]);

    // dual GEMM: lane owns cols [q*8, q*8+8); k = ss*16 + kk
    float aY[8], aZ[8];
    #pragma unroll
    for (int jj = 0; jj < 8; jj++) { aY[jj] = sby[q * 8 + jj]; aZ[jj] = 0.f; }
    #pragma unroll
    for (int kk = 0; kk < 16; kk++) {
        #pragma unroll
        for (int ss = 0; ss < 4; ss++) {
            float v = __shfl(hn[kk], ss, 4);
            int k = ss * 16 + kk;
            const float4* nw = (const float4*)(sNW + k * 32 + q * 8);
            const float4* ew = (const float4*)(sEW + k * 32 + q * 8);
            float4 a = nw[0], b = nw[1], c = ew[0], d = ew[1];
            aY[0] += v * a.x; aY[1] += v * a.y; aY[2] += v * a.z; aY[3] += v * a.w;
            aY[4] += v * b.x; aY[5] += v * b.y; aY[6] += v * b.z; aY[7] += v * b.w;
            aZ[0] += v * c.x; aZ[1] += v * c.y; aZ[2] += v * c.z; aZ[3] += v * c.w;
            aZ[4] += v * d.x; aZ[5] += v * d.y; aZ[6] += v * d.z; aZ[7] += v * d.w;
        }
    }
    float4* yv = (float4*)(Y + (size_t)node * 32 + q * 8);
    float4* zv = (float4*)(Z + (size_t)node * 32 + q * 8);
    yv[0] = make_float4(aY[0], aY[1], aY[2], aY[3]);
    yv[1] = make_float4(aY[4], aY[5], aY[6], aY[7]);
    zv[0] = make_float4(aZ[0], aZ[1], aZ[2], aZ[3]);
    zv[1] = make_float4(aZ[4], aZ[5], aZ[6], aZ[7]);
}

// ---------------------------------------------------------------------------
// Gather: Y[n] += sum over incoming edges of w_e * Z[src_e]  (8 lanes/node)
// ---------------------------------------------------------------------------
__global__ __launch_bounds__(256) void gather_kernel(
    const int* __restrict__ offs, const int2* __restrict__ ep,
    const float* __restrict__ Z, float* __restrict__ Y)
{
    int gid = blockIdx.x * 256 + threadIdx.x;
    int node = gid >> 3;
    int lane = gid & 7;
    if (node >= N_NODES) return;
    int p0 = offs[node], p1 = offs[node + 1];
    float4 acc = make_float4(0.f, 0.f, 0.f, 0.f);
    for (int p = p0; p < p1; p++) {
        int2 pr = ep[p];
        float we = __int_as_float(pr.y);
        float4 zv = ((const float4*)Z)[(size_t)pr.x * 8 + lane];
        acc.x += we * zv.x; acc.y += we * zv.y;
        acc.z += we * zv.z; acc.w += we * zv.w;
    }
    float4* yp = (float4*)(Y + (size_t)node * 32) + lane;
    float4 y = *yp;
    y.x += acc.x; y.y += acc.y; y.z += acc.z; y.w += acc.w;
    *yp = y;
}

// ---------------------------------------------------------------------------
// Kernel B: mlp+residual (layer l) then LN + dual GEMM (layer l+1).
// 4 lanes/node; lane q owns features [q*16,q*16+16), Y/Z cols [q*8,q*8+8).
// ---------------------------------------------------------------------------
__global__ __launch_bounds__(256) void mlp_ln_gemm(
    float* __restrict__ Yio, float* __restrict__ H, float* __restrict__ Z,
    const float* __restrict__ mlpW, const float* __restrict__ mlp_b,
    const float* __restrict__ ln_g, const float* __restrict__ ln_b,
    const float* __restrict__ nodeW, const float* __restrict__ node_b,
    const float* __restrict__ edgeW, const float* __restrict__ edge_b)
{
    __shared__ float sMW[32 * 64];
    __shared__ float sNW[64 * 32];
    __shared__ float sEW[64 * 32];
    __shared__ float smb[64], sg[64], sb[64], sby[32];
    for (int idx = threadIdx.x; idx < 32 * 64; idx += 256) sMW[idx] = mlpW[idx];
    for (int idx = threadIdx.x; idx < 64 * 32; idx += 256) {
        sNW[idx] = nodeW[idx];
        sEW[idx] = edgeW[idx];
    }
    if (threadIdx.x < 64) {
        smb[threadIdx.x] = mlp_b[threadIdx.x];
        sg[threadIdx.x] = ln_g[threadIdx.x];
        sb[threadIdx.x] = ln_b[threadIdx.x];
    }
    if (threadIdx.x < 32) sby[threadIdx.x] = node_b[threadIdx.x] + edge_b[threadIdx.x];
    __syncthreads();

    int gid = blockIdx.x * 256 + threadIdx.x;
    int node = gid >> 2;
    int q = gid & 3;
    if (node >= N_NODES) return;

    // lane holds leaky(Y) for k in [q*8, q*8+8)
    float ly[8];
    const float4* yvin = (const float4*)(Yio + (size_t)node * 32 + q * 8);
    {
        float4 t0 = yvin[0], t1 = yvin[1];
        ly[0] = leaky(t0.x); ly[1] = leaky(t0.y); ly[2] = leaky(t0.z); ly[3] = leaky(t0.w);
        ly[4] = leaky(t1.x); ly[5] = leaky(t1.y); ly[6] = leaky(t1.z); ly[7] = leaky(t1.w);
    }
    // h chunk: j in [q*16, q*16+16); k = ss*8 + kk via shfl
    float h[16];
    #pragma unroll
    for (int jj = 0; jj < 16; jj++) h[jj] = smb[q * 16 + jj];
    #pragma unroll
    for (int kk = 0; kk < 8; kk++) {
        #pragma unroll
        for (int ss = 0; ss < 4; ss++) {
            float v = __shfl(ly[kk], ss, 4);
            const float4* w = (const float4*)(sMW + (ss * 8 + kk) * 64 + q * 16);
            float4 a = w[0], b = w[1], c = w[2], d = w[3];
            h[0]  += v * a.x; h[1]  += v * a.y; h[2]  += v * a.z; h[3]  += v * a.w;
            h[4]  += v * b.x; h[5]  += v * b.y; h[6]  += v * b.z; h[7]  += v * b.w;
            h[8]  += v * c.x; h[9]  += v * c.y; h[10] += v * c.z; h[11] += v * c.w;
            h[12] += v * d.x; h[13] += v * d.y; h[14] += v * d.z; h[15] += v * d.w;
        }
    }
    // residual
    float4* hp = (float4*)(H + (size_t)node * 64 + q * 16);
    #pragma unroll
    for (int c = 0; c < 4; c++) {
        float4 r = hp[c];
        h[4 * c] += r.x; h[4 * c + 1] += r.y; h[4 * c + 2] += r.z; h[4 * c + 3] += r.w;
    }
    // LN over quad
    float s = 0.f, s2 = 0.f;
    #pragma unroll
    for (int jj = 0; jj < 16; jj++) { s += h[jj]; s2 += h[jj] * h[jj]; }
    s  += __shfl_xor(s, 1, 4);  s  += __shfl_xor(s, 2, 4);
    s2 += __shfl_xor(s2, 1, 4); s2 += __shfl_xor(s2, 2, 4);
    float mu  = s * (1.f / 64.f);
    float var = s2 * (1.f / 64.f) - mu * mu;
    float rs  = rsqrtf(var + 1e-5f);

    float hn[16];
    #pragma unroll
    for (int jj = 0; jj < 16; jj++)
        hn[jj] = (h[jj] - mu) * rs * sg[q * 16 + jj] + sb[q * 16 + jj];
    #pragma unroll
    for (int c = 0; c < 4; c++)
        hp[c] = make_float4(hn[4 * c], hn[4 * c + 1], hn[4 * c + 2], hn[4 * c + 3]);

    // dual GEMM
    float aY[8], aZ[8];
    #pragma unroll
    for (int jj = 0; jj < 8; jj++) { aY[jj] = sby[q * 8 + jj]; aZ[jj] = 0.f; }
    #pragma unroll
    for (int kk = 0; kk < 16; kk++) {
        #pragma unroll
        for (int ss = 0; ss < 4; ss++) {
            float v = __shfl(hn[kk], ss, 4);
            int k = ss * 16 + kk;
            const float4* nw = (const float4*)(sNW + k * 32 + q * 8);
            const float4* ew = (const float4*)(sEW + k * 32 + q * 8);
            float4 a = nw[0], b = nw[1], c = ew[0], d = ew[1];
            aY[0] += v * a.x; aY[1] += v * a.y; aY[2] += v * a.z; aY[3] += v * a.w;
            aY[4] += v * b.x; aY[5] += v * b.y; aY[6] += v * b.z; aY[7] += v * b.w;
            aZ[0] += v * c.x; aZ[1] += v * c.y; aZ[2] += v * c.z; aZ[3] += v * c.w;
            aZ[4] += v * d.x; aZ[5] += v * d.y; aZ[6] += v * d.z; aZ[7] += v * d.w;
        }
    }
    float4* yo = (float4*)(Yio + (size_t)node * 32 + q * 8);
    float4* zv = (float4*)(Z + (size_t)node * 32 + q * 8);
    yo[0] = make_float4(aY[0], aY[1], aY[2], aY[3]);
    yo[1] = make_float4(aY[4], aY[5], aY[6], aY[7]);
    zv[0] = make_float4(aZ[0], aZ[1], aZ[2], aZ[3]);
    zv[1] = make_float4(aZ[4], aZ[5], aZ[6], aZ[7]);
}

// ---------------------------------------------------------------------------
// Kernel C: mlp+residual (layer 3) then decoder.  4 lanes/node.
// ---------------------------------------------------------------------------
__global__ __launch_bounds__(256) void mlp_dec(
    const float* __restrict__ Y, const float* __restrict__ H,
    const float* __restrict__ mlpW, const float* __restrict__ mlp_b,
    const float* __restrict__ dW1, const float* __restrict__ db1,
    const float* __restrict__ dW2, const float* __restrict__ db2,
    float* __restrict__ out)
{
    __shared__ float sMW[32 * 64];
    __shared__ float smb[64];
    __shared__ float sW1t[24 * 65];   // [t][k] = dW1[k][t], stride 65 (bank spread)
    __shared__ float sb1[24];
    __shared__ float sW2[24 * 3];
    __shared__ float sb2v[3];
    for (int idx = threadIdx.x; idx < 32 * 64; idx += 256) sMW[idx] = mlpW[idx];
    for (int idx = threadIdx.x; idx < 64 * 24; idx += 256) {
        int k = idx / 24, t = idx % 24;
        sW1t[t * 65 + k] = dW1[idx];
    }
    if (threadIdx.x < 64) smb[threadIdx.x] = mlp_b[threadIdx.x];
    if (threadIdx.x < 24) sb1[threadIdx.x] = db1[threadIdx.x];
    if (threadIdx.x < 72) sW2[threadIdx.x] = dW2[threadIdx.x];
    if (threadIdx.x < 3)  sb2v[threadIdx.x] = db2[threadIdx.x];
    __syncthreads();

    int gid = blockIdx.x * 256 + threadIdx.x;
    int node = gid >> 2;
    int q = gid & 3;
    if (node >= N_NODES) return;

    float ly[8];
    const float4* yvin = (const float4*)(Y + (size_t)node * 32 + q * 8);
    {
        float4 t0 = yvin[0], t1 = yvin[1];
        ly[0] = leaky(t0.x); ly[1] = leaky(t0.y); ly[2] = leaky(t0.z); ly[3] = leaky(t0.w);
        ly[4] = leaky(t1.x); ly[5] = leaky(t1.y); ly[6] = leaky(t1.z); ly[7] = leaky(t1.w);
    }
    float h[16];
    #pragma unroll
    for (int jj = 0; jj < 16; jj++) h[jj] = smb[q * 16 + jj];
    #pragma unroll
    for (int kk = 0; kk < 8; kk++) {
        #pragma unroll
        for (int ss = 0; ss < 4; ss++) {
            float v = __shfl(ly[kk], ss, 4);
            const float4* w = (const float4*)(sMW + (ss * 8 + kk) * 64 + q * 16);
            float4 a = w[0], b = w[1], c = w[2], d = w[3];
            h[0]  += v * a.x; h[1]  += v * a.y; h[2]  += v * a.z; h[3]  += v * a.w;
            h[4]  += v * b.x; h[5]  += v * b.y; h[6]  += v * b.z; h[7]  += v * b.w;
            h[8]  += v * c.x; h[9]  += v * c.y; h[10] += v * c.z; h[11] += v * c.w;
            h[12] += v * d.x; h[13] += v * d.y; h[14] += v * d.z; h[15] += v * d.w;
        }
    }
    const float4* hp = (const float4*)(H + (size_t)node * 64 + q * 16);
    #pragma unroll
    for (int c = 0; c < 4; c++) {
        float4 r = hp[c];
        h[4 * c] += r.x; h[4 * c + 1] += r.y; h[4 * c + 2] += r.z; h[4 * c + 3] += r.w;
    }
    // decoder hidden: lane q owns t in [q*6, q*6+6); k = ss*16+kk via shfl
    float hid[6];
    #pragma unroll
    for (int t = 0; t < 6; t++) hid[t] = sb1[q * 6 + t];
    #pragma unroll
    for (int kk = 0; kk < 16; kk++) {
        #pragma unroll
        for (int ss = 0; ss < 4; ss++) {
            float v = __shfl(h[kk], ss, 4);
            int k = ss * 16 + kk;
            #pragma unroll
            for (int t = 0; t < 6; t++)
                hid[t] += v * sW1t[(q * 6 + t) * 65 + k];
        }
    }
    float o0 = 0.f, o1 = 0.f, o2 = 0.f;
    #pragma unroll
    for (int t = 0; t < 6; t++) {
        float lt = leaky(hid[t]);
        int tg = q * 6 + t;
        o0 += lt * sW2[tg * 3 + 0];
        o1 += lt * sW2[tg * 3 + 1];
        o2 += lt * sW2[tg * 3 + 2];
    }
    o0 += __shfl_xor(o0, 1, 4); o0 += __shfl_xor(o0, 2, 4);
    o1 += __shfl_xor(o1, 1, 4); o1 += __shfl_xor(o1, 2, 4);
    o2 += __shfl_xor(o2, 1, 4); o2 += __shfl_xor(o2, 2, 4);
    if (q == 0) {
        float* op = out + (size_t)node * 3;
        op[0] = o0 + sb2v[0]; op[1] = o1 + sb2v[1]; op[2] = o2 + sb2v[2];
    }
}

// ---------------------------------------------------------------------------
extern "C" void kernel_launch(void* const* d_in, const int* in_sizes, int n_in,
                              void* d_out, int out_size, void* d_ws, size_t ws_size,
                              hipStream_t stream)
{
    const float* x      = (const float*)d_in[0];
    const int*   esrc   = (const int*)d_in[2];
    const int*   edst   = (const int*)d_in[3];
    const float* ew     = (const float*)d_in[4];
    const float* enc_W1 = (const float*)d_in[5];
    const float* enc_b1 = (const float*)d_in[6];
    const float* enc_W2 = (const float*)d_in[7];
    const float* enc_b2 = (const float*)d_in[8];
    const float* dec_W1 = (const float*)d_in[9];
    const float* dec_b1 = (const float*)d_in[10];
    const float* dec_W2 = (const float*)d_in[11];
    const float* dec_b2 = (const float*)d_in[12];
    const float* ln_g   = (const float*)d_in[13];
    const float* ln_b   = (const float*)d_in[14];
    const float* node_W = (const float*)d_in[15];
    const float* node_b = (const float*)d_in[16];
    const float* edge_W = (const float*)d_in[17];
    const float* edge_b = (const float*)d_in[18];
    const float* mlp_W  = (const float*)d_in[19];
    const float* mlp_b  = (const float*)d_in[20];

    // Workspace: floats H[N*64] | Y[N*32] | Z[N*32] | ep[E int2]
    //            ints counts[N] | offs[N+1] | cursor[N] | bsum | bscan
    float* H  = (float*)d_ws;
    float* Y  = H + (size_t)N_NODES * 64;
    float* Z  = Y + (size_t)N_NODES * 32;
    int2*  ep = (int2*)(Z + (size_t)N_NODES * 32);
    int* counts = (int*)(ep + N_EDGES);
    int* offs   = counts + N_NODES;          // N_NODES+1 entries
    int* cursor = offs + N_NODES + 1;
    int* bsum   = cursor + N_NODES;
    int* bscan  = bsum + NB1;

    const int nodeBlocks   = (N_NODES + 255) / 256;
    const int node4Blocks  = (N_NODES * 4 + 255) / 256;
    const int edgeBlocks   = (N_EDGES + 255) / 256;
    const int gatherBlocks = (N_NODES * 8 + 255) / 256;

    // --- CSR build (counting sort by dst) ---
    zero_counts<<<nodeBlocks, 256, 0, stream>>>(counts);
    count_kernel<<<edgeBlocks, 256, 0, stream>>>(edst, counts);
    scan1_kernel<<<NB1, 256, 0, stream>>>(counts, offs, bsum);
    scan2_kernel<<<1, 128, 0, stream>>>(bsum, bscan);
    scan3_kernel<<<NB1, 256, 0, stream>>>(offs, cursor, bscan);
    fill_kernel<<<edgeBlocks, 256, 0, stream>>>(esrc, edst, ew, cursor, ep);

    // --- network ---
    enc_ln_gemm<<<node4Blocks, 256, 0, stream>>>(
        x, enc_W1, enc_b1, enc_W2, enc_b2,
        ln_g, ln_b, node_W, node_b, edge_W, edge_b, H, Y, Z);

    for (int l = 0; l < LAYERS - 1; l++) {
        gather_kernel<<<gatherBlocks, 256, 0, stream>>>(offs, ep, Z, Y);
        mlp_ln_gemm<<<node4Blocks, 256, 0, stream>>>(
            Y, H, Z,
            mlp_W + l * 32 * 64, mlp_b + l * 64,
            ln_g + (l + 1) * 64, ln_b + (l + 1) * 64,
            node_W + (l + 1) * 64 * 32, node_b + (l + 1) * 32,
            edge_W + (l + 1) * 64 * 32, edge_b + (l + 1) * 32);
    }
    gather_kernel<<<gatherBlocks, 256, 0, stream>>>(offs, ep, Z, Y);
    mlp_dec<<<node4Blocks, 256, 0, stream>>>(
        Y, H, mlp_W + 3 * 32 * 64, mlp_b + 3 * 64,
        dec_W1, dec_b1, dec_W2, dec_b2, (float*)d_out);
}